// Round 5
// baseline (233.133 us; speedup 1.0000x reference)
//
#include <hip/hip_runtime.h>
#include <stdint.h>

#define B_  32
#define M_  1024
#define DF  128   // feature dim
#define ED  64    // embedding dim

typedef __attribute__((ext_vector_type(8))) short short8;   // 8 bf16 (4 VGPRs)
typedef __attribute__((ext_vector_type(4))) float floatx4;  // MFMA C/D

__device__ inline unsigned short f2bf(float f) {
    union { float f; unsigned u; } v; v.f = f;
    unsigned r = v.u + 0x7fffu + ((v.u >> 16) & 1u);
    return (unsigned short)(r >> 16);
}

// ---------------------------------------------------------------- cast kernel
__global__ __launch_bounds__(256) void cast_kernel(
    const float* __restrict__ E, const float* __restrict__ W1,
    const float* __restrict__ W2, unsigned short* __restrict__ Ebf,
    unsigned short* __restrict__ W1bf, unsigned short* __restrict__ W2bf) {
    const int NE = B_ * M_ * ED;          // 2,097,152
    const int NW = DF * DF;               // 16,384
    int idx = (blockIdx.x * 256 + threadIdx.x) * 4;
    const float* src; unsigned short* dst; int off;
    if (idx < NE)            { src = E;  dst = Ebf;  off = idx; }
    else if (idx < NE + NW)  { src = W1; dst = W1bf; off = idx - NE; }
    else                     { src = W2; dst = W2bf; off = idx - NE - NW; }
    float4 v = *(const float4*)(src + off);
    ushort4 o;
    o.x = f2bf(v.x); o.y = f2bf(v.y); o.z = f2bf(v.z); o.w = f2bf(v.w);
    *(ushort4*)(dst + off) = o;
}

// ---------------------------------------------------------------- build S + dinv + Xt (fused)
// S[b][m][n] = bf16(relu(e_m.e_n) + (m==n)); dinv = rsqrt(rowsum);
// Xt[b][d][m] = bf16(dinv_m * X[m][d]).  64-row strip per block, no atomics.
__global__ __launch_bounds__(256) void build_s_kernel(
    const unsigned short* __restrict__ Ebf, const float* __restrict__ X,
    unsigned short* __restrict__ S, float* __restrict__ dinv,
    unsigned short* __restrict__ Xt) {
    int mt2 = blockIdx.x, b = blockIdx.y;
    int t = threadIdx.x;
    int w = t >> 6, lane = t & 63, quad = lane >> 4, lc = lane & 15;
    __shared__ unsigned short sEn[128][72];       // 18432 B
    __shared__ unsigned short sOut[128 * 72];     // 18432 B (also Xt transpose buf)
    __shared__ float sDinv[64];
    const unsigned short* Eb = Ebf + (size_t)b * M_ * ED;
    unsigned short* Sg = S + ((size_t)b << 20);
    int m0 = mt2 * 64;
    int base_m = m0 + w * 16;

    short8 afr[2];                                // rows base_m + lc
    for (int ks = 0; ks < 2; ++ks)
        afr[ks] = *(const short8*)(Eb + (size_t)(base_m + lc) * ED + ks * 32 + quad * 8);
    floatx4 rsum = (floatx4){0.f, 0.f, 0.f, 0.f};

    for (int nc = 0; nc < 8; ++nc) {
        __syncthreads();                          // sEn free (prev MFMA reads done)
        for (int it = 0; it < 4; ++it) {
            int c = t + 256 * it;                 // 1024 = 128 rows x 8
            int row = c >> 3, off = (c & 7) * 8;
            *(short8*)(&sEn[row][off]) =
                *(const short8*)(Eb + (size_t)(nc * 128 + row) * ED + off);
        }
        __syncthreads();
        for (int nt = 0; nt < 8; ++nt) {
            short8 b0 = *(const short8*)(&sEn[nt * 16 + lc][quad * 8]);
            short8 b1 = *(const short8*)(&sEn[nt * 16 + lc][32 + quad * 8]);
            floatx4 s = (floatx4){0.f, 0.f, 0.f, 0.f};
            s = __builtin_amdgcn_mfma_f32_16x16x32_bf16(afr[0], b0, s, 0, 0, 0);
            s = __builtin_amdgcn_mfma_f32_16x16x32_bf16(afr[1], b1, s, 0, 0, 0);
            int n = nc * 128 + nt * 16 + lc;
            for (int r = 0; r < 4; ++r) {
                int m = base_m + quad * 4 + r;
                float v = fmaxf(s[r], 0.f);
                if (m == n) v += 1.0f;
                rsum[r] += v;
                // wave-local rows: 64 rows x 128 n, stride 136 u16
                sOut[(w * 16 + quad * 4 + r) * 136 + nt * 16 + lc] = f2bf(v);
            }
        }
        __syncthreads();                          // sOut complete
        for (int it = 0; it < 4; ++it) {          // 64 x 128 = 1024 short8
            int c = t + 256 * it;
            int lrow = c >> 4, noff = (c & 15) * 8;
            *(short8*)(Sg + (size_t)(m0 + lrow) * M_ + nc * 128 + noff) =
                *(const short8*)(&sOut[lrow * 136 + noff]);
        }
    }
    // row sums -> dinv (global + LDS for the fused Xt pass)
    for (int r = 0; r < 4; ++r) {
        float v = rsum[r];
        v += __shfl_xor(v, 1, 16);
        v += __shfl_xor(v, 2, 16);
        v += __shfl_xor(v, 4, 16);
        v += __shfl_xor(v, 8, 16);
        if (lc == 0) {
            float dv = rsqrtf(v);
            int lrow = w * 16 + quad * 4 + r;
            dinv[b * M_ + m0 + lrow] = dv;
            sDinv[lrow] = dv;
        }
    }
    __syncthreads();                              // sDinv ready, sOut stores done
    // ---- fused Xt: read X rows m0..m0+63 (fp32), scale, transpose
    unsigned short* sXT = sOut;                   // [128 d][72] u16
    {
        int nloc = t >> 5;                        // 0..7
        int d4 = (t & 31) * 4;
        for (int pass = 0; pass < 8; ++pass) {
            int n = pass * 8 + nloc;              // 0..63 local row
            float sc = sDinv[n];
            float4 v = *(const float4*)(X + (size_t)(b * M_ + m0 + n) * DF + d4);
            sXT[(d4 + 0) * 72 + n] = f2bf(v.x * sc);
            sXT[(d4 + 1) * 72 + n] = f2bf(v.y * sc);
            sXT[(d4 + 2) * 72 + n] = f2bf(v.z * sc);
            sXT[(d4 + 3) * 72 + n] = f2bf(v.w * sc);
        }
    }
    __syncthreads();
    for (int it = 0; it < 4; ++it) {              // 128 d x 64 m = 1024 short8
        int c = t + 256 * it;
        int d = c >> 3, off = (c & 7) * 8;
        *(short8*)(Xt + (size_t)(b * DF + d) * M_ + m0 + off) =
            *(const short8*)(&sXT[d * 72 + off]);
    }
}

// ---------------------------------------------------------------- GEMM layer (r3 structure + reg dbuf)
// Z[m][d] = sum_n S[m][n] * Pt[d][n]; Y = dinv_m*Z; H = relu(Y @ W^T)
// MODE 1: OutT[b][o][m] = bf16(dinv_m * H);  MODE 2: OutF[m][o] = fp32(H)
template <int MODE>
__global__ __launch_bounds__(256) void gemm_kernel(
    const unsigned short* __restrict__ S,
    const unsigned short* __restrict__ Pt,    // [b][128 d][1024 n] bf16
    const unsigned short* __restrict__ Wbf,   // [128 o][128 i] bf16
    const float* __restrict__ dinv,
    unsigned short* __restrict__ OutT,
    float* __restrict__ OutF) {
    int bx = blockIdx.x, b = blockIdx.y;      // 64 m x 128 d tile
    int m0 = bx * 64;
    int t = threadIdx.x;
    int w = t >> 6, lane = t & 63, quad = lane >> 4, lc = lane & 15;
    int wr = w & 1, wc = w >> 1;              // wave: 32 m x 64 d quadrant

    __shared__ __align__(16) char lds[52224];
    unsigned short* sA = (unsigned short*)lds;            //  64x64 u16 =  8192 B
    unsigned short* sB = (unsigned short*)(lds + 8192);   // 128x64 u16 = 16384 B
    unsigned short* sY = (unsigned short*)lds;            //  64x136 u16 = 17408 B
    unsigned short* sW = (unsigned short*)(lds + 17408);  // 128x136 u16 = 34816 B
    unsigned short* sT = (unsigned short*)(lds + 17408);  // 128x72  u16 = 18432 B

    const unsigned short* Sg = S + ((size_t)b << 20);
    const unsigned short* Pb = Pt + (size_t)b * DF * M_;

    floatx4 acc[2][4];
    for (int i = 0; i < 2; ++i)
        for (int j = 0; j < 4; ++j) acc[i][j] = (floatx4){0.f, 0.f, 0.f, 0.f};

    // register double-buffer: per thread 2 x 16B of sA, 4 x 16B of sB
    uint4 regA[2], regB[4];
    {
        for (int r = 0; r < 2; ++r) {
            int c = r * 256 + t;
            regA[r] = *(const uint4*)(Sg + (size_t)(m0 + (c >> 3)) * M_ + (c & 7) * 8);
        }
        for (int r = 0; r < 4; ++r) {
            int c = r * 256 + t;
            regB[r] = *(const uint4*)(Pb + (size_t)(c >> 3) * M_ + (c & 7) * 8);
        }
    }
    for (int nc = 0; nc < 16; ++nc) {         // BK = 64
        __syncthreads();                      // prev chunk's LDS reads done
        for (int r = 0; r < 2; ++r) {
            int c = r * 256 + t;
            *(uint4*)((char*)sA + c * 16) = regA[r];
        }
        for (int r = 0; r < 4; ++r) {
            int c = r * 256 + t;
            *(uint4*)((char*)sB + c * 16) = regB[r];
        }
        __syncthreads();
        if (nc < 15) {                        // prefetch next chunk (overlaps compute)
            int ko = (nc + 1) * 64;
            for (int r = 0; r < 2; ++r) {
                int c = r * 256 + t;
                regA[r] = *(const uint4*)(Sg + (size_t)(m0 + (c >> 3)) * M_ + ko + (c & 7) * 8);
            }
            for (int r = 0; r < 4; ++r) {
                int c = r * 256 + t;
                regB[r] = *(const uint4*)(Pb + (size_t)(c >> 3) * M_ + ko + (c & 7) * 8);
            }
        }
        for (int ks = 0; ks < 2; ++ks) {
            short8 afr[2], bfr[4];
            for (int i = 0; i < 2; ++i)
                afr[i] = *(const short8*)(&sA[(wr * 32 + i * 16 + lc) * 64 + ks * 32 + quad * 8]);
            for (int j = 0; j < 4; ++j)
                bfr[j] = *(const short8*)(&sB[(wc * 64 + j * 16 + lc) * 64 + ks * 32 + quad * 8]);
            for (int i = 0; i < 2; ++i)
                for (int j = 0; j < 4; ++j)
                    acc[i][j] = __builtin_amdgcn_mfma_f32_16x16x32_bf16(afr[i], bfr[j], acc[i][j], 0, 0, 0);
        }
    }

    // ---- epilogue (r3 verbatim)
    float dv[2][4];
    for (int i = 0; i < 2; ++i)
        for (int r = 0; r < 4; ++r)
            dv[i][r] = dinv[b * M_ + m0 + wr * 32 + i * 16 + quad * 4 + r];
    __syncthreads();                          // main-loop LDS reads done
    for (int i = 0; i < 2; ++i)
        for (int j = 0; j < 4; ++j) {
            int mrow = wr * 32 + i * 16 + quad * 4;
            int col = wc * 64 + j * 16 + lc;
            for (int r = 0; r < 4; ++r)
                sY[(mrow + r) * 136 + col] = f2bf(acc[i][j][r] * dv[i][r]);
        }
    for (int it = 0; it < 8; ++it) {          // W: 128x128 u16 -> 2048 short8
        int c = t + 256 * it;
        int row = c >> 4, off = (c & 15) * 8;
        *(short8*)(&sW[row * 136 + off]) = *(const short8*)(Wbf + row * DF + off);
    }
    __syncthreads();
    floatx4 accH[2][4];
    for (int i = 0; i < 2; ++i)
        for (int j = 0; j < 4; ++j) accH[i][j] = (floatx4){0.f, 0.f, 0.f, 0.f};
    for (int ks = 0; ks < 4; ++ks) {
        short8 afr[2], bfr[4];
        for (int i = 0; i < 2; ++i)
            afr[i] = *(const short8*)(&sY[(wr * 32 + i * 16 + lc) * 136 + ks * 32 + quad * 8]);
        for (int j = 0; j < 4; ++j)
            bfr[j] = *(const short8*)(&sW[(wc * 64 + j * 16 + lc) * 136 + ks * 32 + quad * 8]);
        for (int i = 0; i < 2; ++i)
            for (int j = 0; j < 4; ++j)
                accH[i][j] = __builtin_amdgcn_mfma_f32_16x16x32_bf16(afr[i], bfr[j], accH[i][j], 0, 0, 0);
    }
    if (MODE == 2) {
        float* Ob = OutF + ((size_t)b * M_ + m0) * DF;
        for (int i = 0; i < 2; ++i)
            for (int j = 0; j < 4; ++j) {
                int mrow = wr * 32 + i * 16 + quad * 4;
                int col = wc * 64 + j * 16 + lc;
                for (int r = 0; r < 4; ++r)
                    Ob[(size_t)(mrow + r) * DF + col] = fmaxf(accH[i][j][r], 0.f);
            }
    } else {
        __syncthreads();                      // sW reads done; reuse as sT [128 o][72]
        for (int i = 0; i < 2; ++i)
            for (int j = 0; j < 4; ++j) {
                int mrow = wr * 32 + i * 16 + quad * 4;
                int col = wc * 64 + j * 16 + lc;
                for (int r = 0; r < 4; ++r)
                    sT[col * 72 + mrow + r] = f2bf(fmaxf(accH[i][j][r], 0.f) * dv[i][r]);
            }
        __syncthreads();
        for (int it = 0; it < 4; ++it) {
            int c = t + 256 * it;             // 1024 = 128 o-rows x 8
            int o = c >> 3, moff = (c & 7) * 8;
            *(short8*)(OutT + (size_t)(b * DF + o) * M_ + m0 + moff) =
                *(const short8*)(&sT[o * 72 + moff]);
        }
    }
}

// ---------------------------------------------------------------- launch
extern "C" void kernel_launch(void* const* d_in, const int* in_sizes, int n_in,
                              void* d_out, int out_size, void* d_ws, size_t ws_size,
                              hipStream_t stream) {
    (void)in_sizes; (void)n_in; (void)out_size; (void)ws_size;
    const float* X  = (const float*)d_in[0];   // (B*M, 128)
    const float* E  = (const float*)d_in[1];   // (B*M, 64)
    const float* W1 = (const float*)d_in[2];   // (128, 128)
    const float* W2 = (const float*)d_in[3];   // (128, 128)
    float* out = (float*)d_out;

    char* ws = (char*)d_ws;                    // ~89 MB used
    unsigned short* Ebf  = (unsigned short*)(ws);                    // 4 MB
    unsigned short* W1bf = (unsigned short*)(ws + 4194304);          // 32 KB
    unsigned short* W2bf = (unsigned short*)(ws + 4227072);          // 32 KB
    float*          dinv = (float*)(ws + 4259840);                   // 128 KB
    unsigned short* Xt   = (unsigned short*)(ws + 4390912);          // 8 MB
    unsigned short* Ht   = (unsigned short*)(ws + 12779520);         // 8 MB
    unsigned short* Smat = (unsigned short*)(ws + 21168128);         // 64 MB

    cast_kernel<<<2080, 256, 0, stream>>>(E, W1, W2, Ebf, W1bf, W2bf);
    build_s_kernel<<<dim3(16, 32), 256, 0, stream>>>(Ebf, X, Smat, dinv, Xt);
    gemm_kernel<1><<<dim3(16, 32), 256, 0, stream>>>(Smat, Xt, W1bf, dinv, Ht, nullptr);
    gemm_kernel<2><<<dim3(16, 32), 256, 0, stream>>>(Smat, Ht, W2bf, dinv, nullptr, out);
}

// Round 6
// 155.424 us; speedup vs baseline: 1.5000x; 1.5000x over previous
//
#include <hip/hip_runtime.h>
#include <stdint.h>

#define B_  32
#define M_  1024
#define DF  128   // feature dim
#define ED  64    // embedding dim

typedef __attribute__((ext_vector_type(8))) short short8;   // 8 bf16 (4 VGPRs)
typedef __attribute__((ext_vector_type(4))) float floatx4;  // MFMA C/D

__device__ inline unsigned short f2bf(float f) {
    union { float f; unsigned u; } v; v.f = f;
    unsigned r = v.u + 0x7fffu + ((v.u >> 16) & 1u);
    return (unsigned short)(r >> 16);
}

__device__ inline void load_lds16(const void* g, void* l) {
    __builtin_amdgcn_global_load_lds(
        (const __attribute__((address_space(1))) unsigned int*)g,
        (__attribute__((address_space(3))) unsigned int*)l, 16, 0, 0);
}

// ---------------------------------------------------------------- cast kernel
__global__ __launch_bounds__(256) void cast_kernel(
    const float* __restrict__ E, const float* __restrict__ W1,
    const float* __restrict__ W2, unsigned short* __restrict__ Ebf,
    unsigned short* __restrict__ W1bf, unsigned short* __restrict__ W2bf) {
    const int NE = B_ * M_ * ED;          // 2,097,152
    const int NW = DF * DF;               // 16,384
    int idx = (blockIdx.x * 256 + threadIdx.x) * 4;
    const float* src; unsigned short* dst; int off;
    if (idx < NE)            { src = E;  dst = Ebf;  off = idx; }
    else if (idx < NE + NW)  { src = W1; dst = W1bf; off = idx - NE; }
    else                     { src = W2; dst = W2bf; off = idx - NE - NW; }
    float4 v = *(const float4*)(src + off);
    ushort4 o;
    o.x = f2bf(v.x); o.y = f2bf(v.y); o.z = f2bf(v.z); o.w = f2bf(v.w);
    *(ushort4*)(dst + off) = o;
}

// ---------------------------------------------------------------- build S + dinv + Xt (fused, r5 version - passed)
// S[b][m][n] = bf16(relu(e_m.e_n) + (m==n)); dinv = rsqrt(rowsum);
// Xt[b][d][m] = bf16(dinv_m * X[m][d]).  64-row strip per block, no atomics.
__global__ __launch_bounds__(256) void build_s_kernel(
    const unsigned short* __restrict__ Ebf, const float* __restrict__ X,
    unsigned short* __restrict__ S, float* __restrict__ dinv,
    unsigned short* __restrict__ Xt) {
    int mt2 = blockIdx.x, b = blockIdx.y;
    int t = threadIdx.x;
    int w = t >> 6, lane = t & 63, quad = lane >> 4, lc = lane & 15;
    __shared__ unsigned short sEn[128][72];       // 18432 B
    __shared__ unsigned short sOut[128 * 72];     // 18432 B (also Xt transpose buf)
    __shared__ float sDinv[64];
    const unsigned short* Eb = Ebf + (size_t)b * M_ * ED;
    unsigned short* Sg = S + ((size_t)b << 20);
    int m0 = mt2 * 64;
    int base_m = m0 + w * 16;

    short8 afr[2];                                // rows base_m + lc
    for (int ks = 0; ks < 2; ++ks)
        afr[ks] = *(const short8*)(Eb + (size_t)(base_m + lc) * ED + ks * 32 + quad * 8);
    floatx4 rsum = (floatx4){0.f, 0.f, 0.f, 0.f};

    for (int nc = 0; nc < 8; ++nc) {
        __syncthreads();                          // sEn free (prev MFMA reads done)
        for (int it = 0; it < 4; ++it) {
            int c = t + 256 * it;                 // 1024 = 128 rows x 8
            int row = c >> 3, off = (c & 7) * 8;
            *(short8*)(&sEn[row][off]) =
                *(const short8*)(Eb + (size_t)(nc * 128 + row) * ED + off);
        }
        __syncthreads();
        for (int nt = 0; nt < 8; ++nt) {
            short8 b0 = *(const short8*)(&sEn[nt * 16 + lc][quad * 8]);
            short8 b1 = *(const short8*)(&sEn[nt * 16 + lc][32 + quad * 8]);
            floatx4 s = (floatx4){0.f, 0.f, 0.f, 0.f};
            s = __builtin_amdgcn_mfma_f32_16x16x32_bf16(afr[0], b0, s, 0, 0, 0);
            s = __builtin_amdgcn_mfma_f32_16x16x32_bf16(afr[1], b1, s, 0, 0, 0);
            int n = nc * 128 + nt * 16 + lc;
            for (int r = 0; r < 4; ++r) {
                int m = base_m + quad * 4 + r;
                float v = fmaxf(s[r], 0.f);
                if (m == n) v += 1.0f;
                rsum[r] += v;
                sOut[(w * 16 + quad * 4 + r) * 136 + nt * 16 + lc] = f2bf(v);
            }
        }
        __syncthreads();                          // sOut complete
        for (int it = 0; it < 4; ++it) {          // 64 x 128 = 1024 short8
            int c = t + 256 * it;
            int lrow = c >> 4, noff = (c & 15) * 8;
            *(short8*)(Sg + (size_t)(m0 + lrow) * M_ + nc * 128 + noff) =
                *(const short8*)(&sOut[lrow * 136 + noff]);
        }
    }
    for (int r = 0; r < 4; ++r) {
        float v = rsum[r];
        v += __shfl_xor(v, 1, 16);
        v += __shfl_xor(v, 2, 16);
        v += __shfl_xor(v, 4, 16);
        v += __shfl_xor(v, 8, 16);
        if (lc == 0) {
            float dv = rsqrtf(v);
            int lrow = w * 16 + quad * 4 + r;
            dinv[b * M_ + m0 + lrow] = dv;
            sDinv[lrow] = dv;
        }
    }
    __syncthreads();                              // sDinv ready, sOut stores done
    unsigned short* sXT = sOut;                   // [128 d][72] u16
    {
        int nloc = t >> 5;                        // 0..7
        int d4 = (t & 31) * 4;
        for (int pass = 0; pass < 8; ++pass) {
            int n = pass * 8 + nloc;              // 0..63 local row
            float sc = sDinv[n];
            float4 v = *(const float4*)(X + (size_t)(b * M_ + m0 + n) * DF + d4);
            sXT[(d4 + 0) * 72 + n] = f2bf(v.x * sc);
            sXT[(d4 + 1) * 72 + n] = f2bf(v.y * sc);
            sXT[(d4 + 2) * 72 + n] = f2bf(v.z * sc);
            sXT[(d4 + 3) * 72 + n] = f2bf(v.w * sc);
        }
    }
    __syncthreads();
    for (int it = 0; it < 4; ++it) {              // 128 d x 64 m = 1024 short8
        int c = t + 256 * it;
        int d = c >> 3, off = (c & 7) * 8;
        *(short8*)(Xt + (size_t)(b * DF + d) * M_ + m0 + off) =
            *(const short8*)(&sXT[d * 72 + off]);
    }
}

// ---------------------------------------------------------------- GEMM layer (r3 verbatim: global_load_lds staging)
// Z[m][d] = sum_n S[m][n] * Pt[d][n]; Y = dinv_m*Z; H = relu(Y @ W^T)
// MODE 1: OutT[b][o][m] = bf16(dinv_m * H);  MODE 2: OutF[m][o] = fp32(H)
template <int MODE>
__global__ __launch_bounds__(256) void gemm_kernel(
    const unsigned short* __restrict__ S,
    const unsigned short* __restrict__ Pt,    // [b][128 d][1024 n] bf16
    const unsigned short* __restrict__ Wbf,   // [128 o][128 i] bf16
    const float* __restrict__ dinv,
    unsigned short* __restrict__ OutT,
    float* __restrict__ OutF) {
    int bx = blockIdx.x, b = blockIdx.y;      // 64 m x 128 d tile
    int m0 = bx * 64;
    int t = threadIdx.x;
    int w = t >> 6, lane = t & 63, quad = lane >> 4, lc = lane & 15;
    int wr = w & 1, wc = w >> 1;              // wave: 32 m x 64 d quadrant

    __shared__ __align__(16) unsigned short lds[26112];   // 52,224 B
    unsigned short* sA = lds;                 //  64x64 u16 =  8192 B
    unsigned short* sB = lds + 4096;          // 128x64 u16 = 16384 B
    unsigned short* sY = lds;                 //  64x136 u16 = 17408 B
    unsigned short* sW = lds + 8704;          // 128x136 u16 = 34816 B

    const unsigned short* Sg = S + ((size_t)b << 20);
    const unsigned short* Pb = Pt + (size_t)b * DF * M_;

    floatx4 acc[2][4];
    for (int i = 0; i < 2; ++i)
        for (int j = 0; j < 4; ++j) acc[i][j] = (floatx4){0.f, 0.f, 0.f, 0.f};

    for (int nc = 0; nc < 16; ++nc) {         // BK = 64
        __syncthreads();
        for (int r = 0; r < 2; ++r) {         // sA: 64 x 64 u16 -> 512 x 16B
            int c = r * 256 + w * 64 + lane;
            const void* gp = Sg + (size_t)(m0 + (c >> 3)) * M_ + nc * 64 + (c & 7) * 8;
            load_lds16(gp, (char*)sA + c * 16);
        }
        for (int r = 0; r < 4; ++r) {         // sB: 128 x 64 u16 -> 1024 x 16B
            int c = r * 256 + w * 64 + lane;
            const void* gp = Pb + (size_t)(c >> 3) * M_ + nc * 64 + (c & 7) * 8;
            load_lds16(gp, (char*)sB + c * 16);
        }
        __syncthreads();
        for (int ks = 0; ks < 2; ++ks) {
            short8 afr[2], bfr[4];
            for (int i = 0; i < 2; ++i)
                afr[i] = *(const short8*)(&sA[(wr * 32 + i * 16 + lc) * 64 + ks * 32 + quad * 8]);
            for (int j = 0; j < 4; ++j)
                bfr[j] = *(const short8*)(&sB[(wc * 64 + j * 16 + lc) * 64 + ks * 32 + quad * 8]);
            for (int i = 0; i < 2; ++i)
                for (int j = 0; j < 4; ++j)
                    acc[i][j] = __builtin_amdgcn_mfma_f32_16x16x32_bf16(afr[i], bfr[j], acc[i][j], 0, 0, 0);
        }
    }

    // ---- epilogue
    float dv[2][4];
    for (int i = 0; i < 2; ++i)
        for (int r = 0; r < 4; ++r)
            dv[i][r] = dinv[b * M_ + m0 + wr * 32 + i * 16 + quad * 4 + r];
    __syncthreads();                          // main-loop LDS reads done
    for (int i = 0; i < 2; ++i)
        for (int j = 0; j < 4; ++j) {
            int mrow = wr * 32 + i * 16 + quad * 4;
            int col = wc * 64 + j * 16 + lc;
            for (int r = 0; r < 4; ++r)
                sY[(mrow + r) * 136 + col] = f2bf(acc[i][j][r] * dv[i][r]);
        }
    for (int it = 0; it < 8; ++it) {          // W: 128x128 u16 -> 2048 short8
        int c = t + 256 * it;
        int row = c >> 4, off = (c & 15) * 8;
        *(short8*)(&sW[row * 136 + off]) = *(const short8*)(Wbf + row * DF + off);
    }
    __syncthreads();
    floatx4 accH[2][4];
    for (int i = 0; i < 2; ++i)
        for (int j = 0; j < 4; ++j) accH[i][j] = (floatx4){0.f, 0.f, 0.f, 0.f};
    for (int ks = 0; ks < 4; ++ks) {
        short8 afr[2], bfr[4];
        for (int i = 0; i < 2; ++i)
            afr[i] = *(const short8*)(&sY[(wr * 32 + i * 16 + lc) * 136 + ks * 32 + quad * 8]);
        for (int j = 0; j < 4; ++j)
            bfr[j] = *(const short8*)(&sW[(wc * 64 + j * 16 + lc) * 136 + ks * 32 + quad * 8]);
        for (int i = 0; i < 2; ++i)
            for (int j = 0; j < 4; ++j)
                accH[i][j] = __builtin_amdgcn_mfma_f32_16x16x32_bf16(afr[i], bfr[j], accH[i][j], 0, 0, 0);
    }
    if (MODE == 2) {
        float* Ob = OutF + ((size_t)b * M_ + m0) * DF;
        for (int i = 0; i < 2; ++i)
            for (int j = 0; j < 4; ++j) {
                int mrow = wr * 32 + i * 16 + quad * 4;
                int col = wc * 64 + j * 16 + lc;
                for (int r = 0; r < 4; ++r)
                    Ob[(size_t)(mrow + r) * DF + col] = fmaxf(accH[i][j][r], 0.f);
            }
    } else {
        __syncthreads();                      // sW reads done; reuse as sT [128 o][72]
        unsigned short* sT = sW;
        for (int i = 0; i < 2; ++i)
            for (int j = 0; j < 4; ++j) {
                int mrow = wr * 32 + i * 16 + quad * 4;
                int col = wc * 64 + j * 16 + lc;
                for (int r = 0; r < 4; ++r)
                    sT[col * 72 + mrow + r] = f2bf(fmaxf(accH[i][j][r], 0.f) * dv[i][r]);
            }
        __syncthreads();
        for (int it = 0; it < 4; ++it) {
            int c = t + 256 * it;             // 1024 = 128 o-rows x 8
            int o = c >> 3, moff = (c & 7) * 8;
            *(short8*)(OutT + (size_t)(b * DF + o) * M_ + m0 + moff) =
                *(const short8*)(&sT[o * 72 + moff]);
        }
    }
}

// ---------------------------------------------------------------- launch
extern "C" void kernel_launch(void* const* d_in, const int* in_sizes, int n_in,
                              void* d_out, int out_size, void* d_ws, size_t ws_size,
                              hipStream_t stream) {
    (void)in_sizes; (void)n_in; (void)out_size; (void)ws_size;
    const float* X  = (const float*)d_in[0];   // (B*M, 128)
    const float* E  = (const float*)d_in[1];   // (B*M, 64)
    const float* W1 = (const float*)d_in[2];   // (128, 128)
    const float* W2 = (const float*)d_in[3];   // (128, 128)
    float* out = (float*)d_out;

    char* ws = (char*)d_ws;                    // ~89 MB used
    unsigned short* Ebf  = (unsigned short*)(ws);                    // 4 MB
    unsigned short* W1bf = (unsigned short*)(ws + 4194304);          // 32 KB
    unsigned short* W2bf = (unsigned short*)(ws + 4227072);          // 32 KB
    float*          dinv = (float*)(ws + 4259840);                   // 128 KB
    unsigned short* Xt   = (unsigned short*)(ws + 4390912);          // 8 MB
    unsigned short* Ht   = (unsigned short*)(ws + 12779520);         // 8 MB
    unsigned short* Smat = (unsigned short*)(ws + 21168128);         // 64 MB

    cast_kernel<<<2080, 256, 0, stream>>>(E, W1, W2, Ebf, W1bf, W2bf);
    build_s_kernel<<<dim3(16, 32), 256, 0, stream>>>(Ebf, X, Smat, dinv, Xt);
    gemm_kernel<1><<<dim3(16, 32), 256, 0, stream>>>(Smat, Xt, W1bf, dinv, Ht, nullptr);
    gemm_kernel<2><<<dim3(16, 32), 256, 0, stream>>>(Smat, Ht, W2bf, dinv, nullptr, out);
}